// Round 8
// baseline (284.520 us; speedup 1.0000x reference)
//
#include <hip/hip_runtime.h>
#include <hip/hip_bf16.h>

#define NN 8192
#define NE 262144

typedef __attribute__((ext_vector_type(8))) short bf16x8;
typedef __attribute__((ext_vector_type(4))) float f32x4;
typedef __attribute__((ext_vector_type(16))) float f32x16;
typedef unsigned short u16;
typedef __attribute__((ext_vector_type(4))) u16 u16x4;

__device__ inline u16 f2b(float f) {
  unsigned u = __float_as_uint(f);
  unsigned r = u + 0x7FFF + ((u >> 16) & 1);   // RNE to bf16
  return (u16)(r >> 16);
}
__device__ inline float b2f(u16 b) {
  return __uint_as_float(((unsigned)b) << 16);
}

// ---------- converts ----------
__global__ void split_x(const float* __restrict__ in, u16* __restrict__ hi,
                        u16* __restrict__ lo) {
  int i = (blockIdx.x * blockDim.x + threadIdx.x) * 4;
  f32x4 v = *(const f32x4*)(in + i);
  u16x4 vh, vl;
#pragma unroll
  for (int j = 0; j < 4; ++j) {
    u16 h = f2b(v[j]);
    vh[j] = h;
    vl[j] = f2b(v[j] - b2f(h));
  }
  *(u16x4*)(hi + i) = vh;
  *(u16x4*)(lo + i) = vl;
}

// W1 [512][256] row-major -> col-major [256][512] hi/lo
__global__ void splitT_w1(const float* __restrict__ in, u16* __restrict__ hi,
                          u16* __restrict__ lo) {
  int i = blockIdx.x * blockDim.x + threadIdx.x;  // 512*256
  int k = i >> 8, n = i & 255;
  float v = in[i];
  u16 h = f2b(v);
  hi[(size_t)n * 512 + k] = h;
  lo[(size_t)n * 512 + k] = f2b(v - b2f(h));
}

// W23 col-major [256 cols][256 k]: col j<128 = W2[:,j], j>=128 = W3[:,j-128]
__global__ void build_w23T(const float* __restrict__ W2, const float* __restrict__ W3,
                           u16* __restrict__ hi, u16* __restrict__ lo) {
  int i = blockIdx.x * blockDim.x + threadIdx.x;  // 65536
  int k = i >> 8, j = i & 255;
  float v = (j < 128) ? W2[(k << 7) + j] : W3[(k << 7) + (j - 128)];
  u16 h = f2b(v);
  hi[(size_t)j * 256 + k] = h;
  lo[(size_t)j * 256 + k] = f2b(v - b2f(h));
}

// ---------- CSR build ----------
__global__ void hist_kernel(const int* __restrict__ dst, int* __restrict__ deg) {
  int i = blockIdx.x * blockDim.x + threadIdx.x;
  if (i < NE) atomicAdd(&deg[dst[i]], 1);
}

__global__ void scan_kernel(const int* __restrict__ deg, int* __restrict__ rowptr,
                            int* __restrict__ cursor) {
  __shared__ int sums[1024];
  int t = threadIdx.x;
  int loc[8];
  int s = 0;
#pragma unroll
  for (int j = 0; j < 8; ++j) { s += deg[t * 8 + j]; loc[j] = s; }
  sums[t] = s;
  __syncthreads();
  for (int off = 1; off < 1024; off <<= 1) {
    int v = (t >= off) ? sums[t - off] : 0;
    __syncthreads();
    sums[t] += v;
    __syncthreads();
  }
  int base = (t > 0) ? sums[t - 1] : 0;
  if (t == 0) rowptr[0] = 0;
#pragma unroll
  for (int j = 0; j < 8; ++j) {
    rowptr[t * 8 + j + 1] = base + loc[j];
    cursor[t * 8 + j] = base + (j ? loc[j - 1] : 0);
  }
}

__global__ void scatter_kernel(const int* __restrict__ src, const int* __restrict__ dst,
                               const float* __restrict__ w, int* cursor,
                               int* __restrict__ csr_src, float* __restrict__ csr_w) {
  int i = blockIdx.x * blockDim.x + threadIdx.x;
  if (i >= NE) return;
  int d = dst[i];
  int p = atomicAdd(&cursor[d], 1);
  csr_src[p] = src[i];
  csr_w[p] = w[i];
}

// ---------- split GEMM: C = A(MxK)@B(KxN) f32 out; B packed col-major ----------
// block 256 / 4 waves; wave = 16 rows x 64 cols; grid (M/64, N/64)
__global__ void gemm_split_kernel(const u16* __restrict__ Ah, const u16* __restrict__ Al,
                                  const u16* __restrict__ Bh, const u16* __restrict__ Bl,
                                  float* __restrict__ C, int M, int N, int K) {
  int wave = threadIdx.x >> 6, lane = threadIdx.x & 63;
  int r = lane & 15, kf = (lane >> 4) * 8;
  int row = blockIdx.x * 64 + wave * 16 + r;
  int col0 = blockIdx.y * 64;
  f32x4 acc[4] = {};
  for (int k0 = 0; k0 < K; k0 += 32) {
    int ka = k0 + kf;
    bf16x8 ah = *(const bf16x8*)(Ah + (size_t)row * K + ka);
    bf16x8 al = *(const bf16x8*)(Al + (size_t)row * K + ka);
#pragma unroll
    for (int t = 0; t < 4; ++t) {
      int col = col0 + t * 16 + r;
      bf16x8 bh = *(const bf16x8*)(Bh + (size_t)col * K + ka);
      bf16x8 bl = *(const bf16x8*)(Bl + (size_t)col * K + ka);
      acc[t] = __builtin_amdgcn_mfma_f32_16x16x32_bf16(ah, bh, acc[t], 0, 0, 0);
      acc[t] = __builtin_amdgcn_mfma_f32_16x16x32_bf16(al, bh, acc[t], 0, 0, 0);
      acc[t] = __builtin_amdgcn_mfma_f32_16x16x32_bf16(ah, bl, acc[t], 0, 0, 0);
    }
  }
  int orow = blockIdx.x * 64 + wave * 16 + (lane >> 4) * 4;
#pragma unroll
  for (int t = 0; t < 4; ++t)
#pragma unroll
    for (int q = 0; q < 4; ++q)
      C[(size_t)(orow + q) * N + col0 + t * 16 + r] = acc[t][q];
}

// ---------- spmm (CSR): 4 nodes/block, 64 lanes/node, float4 gather ----------
__global__ void spmm_relu_kernel(const int* __restrict__ rowptr, const int* __restrict__ csr_src,
                                 const float* __restrict__ csr_w, const float* __restrict__ h,
                                 u16* __restrict__ oh, u16* __restrict__ ol) {
  int n = blockIdx.x * 4 + (threadIdx.x >> 6);
  int c = (threadIdx.x & 63) * 4;
  int e0 = rowptr[n], e1 = rowptr[n + 1];
  f32x4 acc = {};
  int i = e0;
  for (; i + 2 <= e1; i += 2) {
    int s0 = csr_src[i], s1 = csr_src[i + 1];
    float w0 = csr_w[i], w1 = csr_w[i + 1];
    f32x4 v0 = *(const f32x4*)(h + (size_t)s0 * 256 + c);
    f32x4 v1 = *(const f32x4*)(h + (size_t)s1 * 256 + c);
#pragma unroll
    for (int j = 0; j < 4; ++j)
      acc[j] = fmaf(w1, v1[j], fmaf(w0, v0[j], acc[j]));
  }
  if (i < e1) {
    float w0 = csr_w[i];
    f32x4 v0 = *(const f32x4*)(h + (size_t)csr_src[i] * 256 + c);
#pragma unroll
    for (int j = 0; j < 4; ++j) acc[j] = fmaf(w0, v0[j], acc[j]);
  }
  u16x4 vh, vl;
#pragma unroll
  for (int j = 0; j < 4; ++j) {
    float a = fmaxf(acc[j], 0.f);
    u16 hb = f2b(a);
    vh[j] = hb;
    vl[j] = f2b(a - b2f(hb));
  }
  *(u16x4*)(oh + (size_t)n * 256 + c) = vh;
  *(u16x4*)(ol + (size_t)n * 256 + c) = vl;
}

__global__ void spmm_out_kernel(const int* __restrict__ rowptr, const int* __restrict__ csr_src,
                                const float* __restrict__ csr_w, const float* __restrict__ h,
                                float* __restrict__ mu, float* __restrict__ logvar,
                                float* __restrict__ z, u16* __restrict__ zb) {
  int n = blockIdx.x * 4 + (threadIdx.x >> 6);
  int c = (threadIdx.x & 63) * 4;
  int e0 = rowptr[n], e1 = rowptr[n + 1];
  f32x4 acc = {};
  int i = e0;
  for (; i + 2 <= e1; i += 2) {
    int s0 = csr_src[i], s1 = csr_src[i + 1];
    float w0 = csr_w[i], w1 = csr_w[i + 1];
    f32x4 v0 = *(const f32x4*)(h + (size_t)s0 * 256 + c);
    f32x4 v1 = *(const f32x4*)(h + (size_t)s1 * 256 + c);
#pragma unroll
    for (int j = 0; j < 4; ++j)
      acc[j] = fmaf(w1, v1[j], fmaf(w0, v0[j], acc[j]));
  }
  if (i < e1) {
    float w0 = csr_w[i];
    f32x4 v0 = *(const f32x4*)(h + (size_t)csr_src[i] * 256 + c);
#pragma unroll
    for (int j = 0; j < 4; ++j) acc[j] = fmaf(w0, v0[j], acc[j]);
  }
  if (c < 128) {
    *(f32x4*)(mu + (size_t)n * 128 + c) = acc;
    *(f32x4*)(z + (size_t)n * 128 + c) = acc;
    u16x4 vb;
#pragma unroll
    for (int j = 0; j < 4; ++j) vb[j] = f2b(acc[j]);
    *(u16x4*)(zb + (size_t)n * 128 + c) = vb;
  } else {
    *(f32x4*)(logvar + (size_t)n * 128 + (c - 128)) = acc;
  }
}

// ---------- adj = Z @ Z^T, Z [8192][128] bf16 ----------
// v4: fill-style ownership. Block = 32 full C rows = contiguous 1MB region.
// 512 thr / 8 waves; wave w owns cols w*1024..+1024 (8 j-tiles of 128).
// A-frags in registers; B-frags read directly from global (Z = 2MB, L2-resident).
// No LDS. Grid = 256 blocks (1/CU).
__global__ void __launch_bounds__(512) zzt_kernel(const u16* __restrict__ Z,
                                                  float* __restrict__ C) {
  int t = threadIdx.x;
  int wave = t >> 6, lane = t & 63;
  int lrow = lane & 31, hi = lane >> 5;
  int i0 = blockIdx.x * 32;
  // A fragments: 32 rows x K=128, lane holds rows i0+lrow, k = ks*16+hi*8..+8
  const u16* aRow = Z + (size_t)(i0 + lrow) * 128 + hi * 8;
  bf16x8 a[8];
#pragma unroll
  for (int ks = 0; ks < 8; ++ks)
    a[ks] = *(const bf16x8*)(aRow + ks * 16);
#pragma unroll 1
  for (int jt = 0; jt < 8; ++jt) {
    int j0 = wave * 1024 + jt * 128;
    f32x16 acc[4] = {};
#pragma unroll
    for (int ks = 0; ks < 8; ++ks) {
#pragma unroll
      for (int tt = 0; tt < 4; ++tt) {
        bf16x8 b = *(const bf16x8*)(Z + (size_t)(j0 + tt * 32 + lrow) * 128 +
                                    ks * 16 + hi * 8);
        acc[tt] = __builtin_amdgcn_mfma_f32_32x32x16_bf16(a[ks], b, acc[tt], 0, 0, 0);
      }
    }
    int rbase = i0 + 4 * hi;
    int col = lane & 31;
#pragma unroll
    for (int tt = 0; tt < 4; ++tt) {
#pragma unroll
      for (int reg = 0; reg < 16; ++reg) {
        int rr = rbase + (reg & 3) + 8 * (reg >> 2);
        __builtin_nontemporal_store(acc[tt][reg],
            &C[(size_t)rr * NN + j0 + tt * 32 + col]);
      }
    }
  }
}

extern "C" void kernel_launch(void* const* d_in, const int* in_sizes, int n_in,
                              void* d_out, int out_size, void* d_ws, size_t ws_size,
                              hipStream_t stream) {
  const float* x  = (const float*)d_in[0];
  const int*   ei = (const int*)d_in[1];
  const float* ew = (const float*)d_in[2];
  const float* W1 = (const float*)d_in[3];
  const float* W2 = (const float*)d_in[4];
  const float* W3 = (const float*)d_in[5];

  float* out    = (float*)d_out;
  float* adj    = out;                                   // [8192,8192]
  float* mu     = out + (size_t)NN * NN;                 // [8192,128]
  float* logv   = mu + (size_t)NN * 128;                 // [8192,128]
  float* z      = logv + (size_t)NN * 128;               // [8192,128]

  const int* srcp = ei;
  const int* dstp = ei + NE;

  char* ws = (char*)d_ws;
  size_t off = 0;
  auto alloc = [&](size_t b) -> void* {
    void* p = ws + off;
    off = (off + b + 255) & ~(size_t)255;
    return p;
  };
  u16* xh   = (u16*)alloc((size_t)NN * 512 * 2);
  u16* xl   = (u16*)alloc((size_t)NN * 512 * 2);
  u16* W1h  = (u16*)alloc(512 * 256 * 2);   // col-major [256][512]
  u16* W1l  = (u16*)alloc(512 * 256 * 2);
  u16* W23h = (u16*)alloc(256 * 256 * 2);   // col-major [256][256]
  u16* W23l = (u16*)alloc(256 * 256 * 2);
  float* h0 = (float*)alloc((size_t)NN * 256 * 4);
  u16* h1h  = (u16*)alloc((size_t)NN * 256 * 2);
  u16* h1l  = (u16*)alloc((size_t)NN * 256 * 2);
  float* H2 = (float*)alloc((size_t)NN * 256 * 4);
  u16* zb   = (u16*)alloc((size_t)NN * 128 * 2);
  int* deg      = (int*)alloc(NN * 4);
  int* rowptr   = (int*)alloc((NN + 1) * 4);
  int* cursor   = (int*)alloc(NN * 4);
  int* csr_src  = (int*)alloc((size_t)NE * 4);
  float* csr_w  = (float*)alloc((size_t)NE * 4);

  hipMemsetAsync(deg, 0, NN * 4, stream);

  // converts
  split_x<<<(NN * 512 / 4) / 256, 256, 0, stream>>>(x, xh, xl);
  splitT_w1<<<(512 * 256) / 256, 256, 0, stream>>>(W1, W1h, W1l);
  build_w23T<<<(256 * 256) / 256, 256, 0, stream>>>(W2, W3, W23h, W23l);

  // CSR build
  hist_kernel<<<NE / 256, 256, 0, stream>>>(dstp, deg);
  scan_kernel<<<1, 1024, 0, stream>>>(deg, rowptr, cursor);
  scatter_kernel<<<NE / 256, 256, 0, stream>>>(srcp, dstp, ew, cursor, csr_src, csr_w);

  // h0 = x @ W1 (f32)
  gemm_split_kernel<<<dim3(NN / 64, 256 / 64), 256, 0, stream>>>(xh, xl, W1h, W1l, h0,
                                                                 NN, 256, 512);
  // h1 = relu(spmm(h0)) -> split hi/lo
  spmm_relu_kernel<<<NN / 4, 256, 0, stream>>>(rowptr, csr_src, csr_w, h0, h1h, h1l);
  // H2 = h1 @ [W2|W3] (f32)
  gemm_split_kernel<<<dim3(NN / 64, 256 / 64), 256, 0, stream>>>(h1h, h1l, W23h, W23l, H2,
                                                                 NN, 256, 256);
  // mu/logvar = spmm(H2); z = mu; zb = bf16(mu)
  spmm_out_kernel<<<NN / 4, 256, 0, stream>>>(rowptr, csr_src, csr_w, H2, mu, logv, z, zb);
  // adj = z @ z^T  (contiguous 1MB per block, B from L2, no LDS)
  zzt_kernel<<<256, 512, 0, stream>>>(zb, adj);
}

// Round 9
// 215.299 us; speedup vs baseline: 1.3215x; 1.3215x over previous
//
#include <hip/hip_runtime.h>
#include <hip/hip_bf16.h>

#define NN 8192
#define NE 262144

typedef __attribute__((ext_vector_type(8))) short bf16x8;
typedef __attribute__((ext_vector_type(4))) float f32x4;
typedef __attribute__((ext_vector_type(16))) float f32x16;
typedef unsigned short u16;
typedef __attribute__((ext_vector_type(4))) u16 u16x4;

__device__ inline u16 f2b(float f) {
  unsigned u = __float_as_uint(f);
  unsigned r = u + 0x7FFF + ((u >> 16) & 1);   // RNE to bf16
  return (u16)(r >> 16);
}
__device__ inline float b2f(u16 b) {
  return __uint_as_float(((unsigned)b) << 16);
}

// ---------- converts ----------
__global__ void split_x(const float* __restrict__ in, u16* __restrict__ hi,
                        u16* __restrict__ lo) {
  int i = (blockIdx.x * blockDim.x + threadIdx.x) * 4;
  f32x4 v = *(const f32x4*)(in + i);
  u16x4 vh, vl;
#pragma unroll
  for (int j = 0; j < 4; ++j) {
    u16 h = f2b(v[j]);
    vh[j] = h;
    vl[j] = f2b(v[j] - b2f(h));
  }
  *(u16x4*)(hi + i) = vh;
  *(u16x4*)(lo + i) = vl;
}

// plain f32 -> bf16 (RNE), 4 elems/thread
__global__ void conv_bf16(const float* __restrict__ in, u16* __restrict__ out) {
  int i = (blockIdx.x * blockDim.x + threadIdx.x) * 4;
  f32x4 v = *(const f32x4*)(in + i);
  u16x4 o;
#pragma unroll
  for (int j = 0; j < 4; ++j) o[j] = f2b(v[j]);
  *(u16x4*)(out + i) = o;
}

// W1 [512][256] row-major -> col-major [256][512] hi/lo
__global__ void splitT_w1(const float* __restrict__ in, u16* __restrict__ hi,
                          u16* __restrict__ lo) {
  int i = blockIdx.x * blockDim.x + threadIdx.x;  // 512*256
  int k = i >> 8, n = i & 255;
  float v = in[i];
  u16 h = f2b(v);
  hi[(size_t)n * 512 + k] = h;
  lo[(size_t)n * 512 + k] = f2b(v - b2f(h));
}

// W23 col-major [256 cols][256 k]: col j<128 = W2[:,j], j>=128 = W3[:,j-128]
__global__ void build_w23T(const float* __restrict__ W2, const float* __restrict__ W3,
                           u16* __restrict__ hi, u16* __restrict__ lo) {
  int i = blockIdx.x * blockDim.x + threadIdx.x;  // 65536
  int k = i >> 8, j = i & 255;
  float v = (j < 128) ? W2[(k << 7) + j] : W3[(k << 7) + (j - 128)];
  u16 h = f2b(v);
  hi[(size_t)j * 256 + k] = h;
  lo[(size_t)j * 256 + k] = f2b(v - b2f(h));
}

// ---------- CSR build ----------
__global__ void hist_kernel(const int* __restrict__ dst, int* __restrict__ deg) {
  int i = blockIdx.x * blockDim.x + threadIdx.x;
  if (i < NE) atomicAdd(&deg[dst[i]], 1);
}

__global__ void scan_kernel(const int* __restrict__ deg, int* __restrict__ rowptr,
                            int* __restrict__ cursor) {
  __shared__ int sums[1024];
  int t = threadIdx.x;
  int loc[8];
  int s = 0;
#pragma unroll
  for (int j = 0; j < 8; ++j) { s += deg[t * 8 + j]; loc[j] = s; }
  sums[t] = s;
  __syncthreads();
  for (int off = 1; off < 1024; off <<= 1) {
    int v = (t >= off) ? sums[t - off] : 0;
    __syncthreads();
    sums[t] += v;
    __syncthreads();
  }
  int base = (t > 0) ? sums[t - 1] : 0;
  if (t == 0) rowptr[0] = 0;
#pragma unroll
  for (int j = 0; j < 8; ++j) {
    rowptr[t * 8 + j + 1] = base + loc[j];
    cursor[t * 8 + j] = base + (j ? loc[j - 1] : 0);
  }
}

__global__ void scatter_kernel(const int* __restrict__ src, const int* __restrict__ dst,
                               const float* __restrict__ w, int* cursor,
                               int* __restrict__ csr_src, float* __restrict__ csr_w) {
  int i = blockIdx.x * blockDim.x + threadIdx.x;
  if (i >= NE) return;
  int d = dst[i];
  int p = atomicAdd(&cursor[d], 1);
  csr_src[p] = src[i];
  csr_w[p] = w[i];
}

// ---------- split GEMM: C = A(MxK)@B(KxN) f32 out; B packed col-major ----------
// block 256 / 4 waves; wave = 16 rows x 64 cols; grid (M/64, N/64)
__global__ void gemm_split_kernel(const u16* __restrict__ Ah, const u16* __restrict__ Al,
                                  const u16* __restrict__ Bh, const u16* __restrict__ Bl,
                                  float* __restrict__ C, int M, int N, int K) {
  int wave = threadIdx.x >> 6, lane = threadIdx.x & 63;
  int r = lane & 15, kf = (lane >> 4) * 8;
  int row = blockIdx.x * 64 + wave * 16 + r;
  int col0 = blockIdx.y * 64;
  f32x4 acc[4] = {};
  for (int k0 = 0; k0 < K; k0 += 32) {
    int ka = k0 + kf;
    bf16x8 ah = *(const bf16x8*)(Ah + (size_t)row * K + ka);
    bf16x8 al = *(const bf16x8*)(Al + (size_t)row * K + ka);
#pragma unroll
    for (int t = 0; t < 4; ++t) {
      int col = col0 + t * 16 + r;
      bf16x8 bh = *(const bf16x8*)(Bh + (size_t)col * K + ka);
      bf16x8 bl = *(const bf16x8*)(Bl + (size_t)col * K + ka);
      acc[t] = __builtin_amdgcn_mfma_f32_16x16x32_bf16(ah, bh, acc[t], 0, 0, 0);
      acc[t] = __builtin_amdgcn_mfma_f32_16x16x32_bf16(al, bh, acc[t], 0, 0, 0);
      acc[t] = __builtin_amdgcn_mfma_f32_16x16x32_bf16(ah, bl, acc[t], 0, 0, 0);
    }
  }
  int orow = blockIdx.x * 64 + wave * 16 + (lane >> 4) * 4;
#pragma unroll
  for (int t = 0; t < 4; ++t)
#pragma unroll
    for (int q = 0; q < 4; ++q)
      C[(size_t)(orow + q) * N + col0 + t * 16 + r] = acc[t][q];
}

// ---------- spmm (CSR): 4 nodes/block, 64 lanes/node, bf16x4 gather ----------
__global__ void spmm_relu_kernel(const int* __restrict__ rowptr, const int* __restrict__ csr_src,
                                 const float* __restrict__ csr_w, const u16* __restrict__ h,
                                 u16* __restrict__ oh, u16* __restrict__ ol) {
  int n = blockIdx.x * 4 + (threadIdx.x >> 6);
  int c = (threadIdx.x & 63) * 4;
  int e0 = rowptr[n], e1 = rowptr[n + 1];
  f32x4 acc = {};
  int i = e0;
  for (; i + 2 <= e1; i += 2) {
    int s0 = csr_src[i], s1 = csr_src[i + 1];
    float w0 = csr_w[i], w1 = csr_w[i + 1];
    u16x4 v0 = *(const u16x4*)(h + (size_t)s0 * 256 + c);
    u16x4 v1 = *(const u16x4*)(h + (size_t)s1 * 256 + c);
#pragma unroll
    for (int j = 0; j < 4; ++j)
      acc[j] = fmaf(w1, b2f(v1[j]), fmaf(w0, b2f(v0[j]), acc[j]));
  }
  if (i < e1) {
    float w0 = csr_w[i];
    u16x4 v0 = *(const u16x4*)(h + (size_t)csr_src[i] * 256 + c);
#pragma unroll
    for (int j = 0; j < 4; ++j) acc[j] = fmaf(w0, b2f(v0[j]), acc[j]);
  }
  u16x4 vh, vl;
#pragma unroll
  for (int j = 0; j < 4; ++j) {
    float a = fmaxf(acc[j], 0.f);
    u16 hb = f2b(a);
    vh[j] = hb;
    vl[j] = f2b(a - b2f(hb));
  }
  *(u16x4*)(oh + (size_t)n * 256 + c) = vh;
  *(u16x4*)(ol + (size_t)n * 256 + c) = vl;
}

__global__ void spmm_out_kernel(const int* __restrict__ rowptr, const int* __restrict__ csr_src,
                                const float* __restrict__ csr_w, const u16* __restrict__ h,
                                float* __restrict__ mu, float* __restrict__ logvar,
                                float* __restrict__ z, u16* __restrict__ zb) {
  int n = blockIdx.x * 4 + (threadIdx.x >> 6);
  int c = (threadIdx.x & 63) * 4;
  int e0 = rowptr[n], e1 = rowptr[n + 1];
  f32x4 acc = {};
  int i = e0;
  for (; i + 2 <= e1; i += 2) {
    int s0 = csr_src[i], s1 = csr_src[i + 1];
    float w0 = csr_w[i], w1 = csr_w[i + 1];
    u16x4 v0 = *(const u16x4*)(h + (size_t)s0 * 256 + c);
    u16x4 v1 = *(const u16x4*)(h + (size_t)s1 * 256 + c);
#pragma unroll
    for (int j = 0; j < 4; ++j)
      acc[j] = fmaf(w1, b2f(v1[j]), fmaf(w0, b2f(v0[j]), acc[j]));
  }
  if (i < e1) {
    float w0 = csr_w[i];
    u16x4 v0 = *(const u16x4*)(h + (size_t)csr_src[i] * 256 + c);
#pragma unroll
    for (int j = 0; j < 4; ++j) acc[j] = fmaf(w0, b2f(v0[j]), acc[j]);
  }
  if (c < 128) {
    *(f32x4*)(mu + (size_t)n * 128 + c) = acc;
    *(f32x4*)(z + (size_t)n * 128 + c) = acc;
    u16x4 vb;
#pragma unroll
    for (int j = 0; j < 4; ++j) vb[j] = f2b(acc[j]);
    *(u16x4*)(zb + (size_t)n * 128 + c) = vb;
  } else {
    *(f32x4*)(logvar + (size_t)n * 128 + (c - 128)) = acc;
  }
}

// ---------- adj = Z @ Z^T, Z [8192][128] bf16 ----------
// v3b (R7): A in registers, B in 32KB swizzled LDS -> 4 blocks/CU.
// block 256 / 4 waves; tile 128x128; wave = 32 rows x 128 cols; grid (64,64).
__global__ void zzt_kernel(const u16* __restrict__ Z, float* __restrict__ C) {
  __shared__ u16 lB[128 * 128];   // 32KB swizzled (rows = C cols)
  int t = threadIdx.x;
  int i0 = blockIdx.y * 128;
  int j0 = blockIdx.x * 128;
  // stage B: 32KB = 8 chunks x 256 threads x 16B, sequential + swizzled write
  const char* gB = (const char*)(Z + (size_t)j0 * 128);
#pragma unroll
  for (int cix = 0; cix < 8; ++cix) {
    int p = (cix * 256 + t) * 16;
    int row = p >> 8;
    int sw = (p & 255) ^ ((row & 15) << 4);
    bf16x8 vb = *(const bf16x8*)(gB + p);
    *(bf16x8*)((char*)lB + row * 256 + sw) = vb;
  }
  // A in registers: lane holds its MFMA A-fragment rows directly
  int wave = t >> 6, lane = t & 63;
  int lrow = lane & 31, hi = lane >> 5;
  const u16* aRow = Z + (size_t)(i0 + wave * 32 + lrow) * 128 + hi * 8;
  bf16x8 a[8];
#pragma unroll
  for (int k = 0; k < 8; ++k)
    a[k] = *(const bf16x8*)(aRow + k * 16);
  __syncthreads();
  f32x16 acc[4] = {};
#pragma unroll
  for (int ks = 0; ks < 8; ++ks) {
    int kb = ks * 32 + hi * 16;          // byte offset within 256B row
#pragma unroll
    for (int tt = 0; tt < 4; ++tt) {
      int brow = tt * 32 + lrow;
      bf16x8 b = *(const bf16x8*)((const char*)lB + brow * 256 + (kb ^ ((brow & 15) << 4)));
      acc[tt] = __builtin_amdgcn_mfma_f32_32x32x16_bf16(a[ks], b, acc[tt], 0, 0, 0);
    }
  }
  int rb = wave * 32 + 4 * (lane >> 5);
  int col = lane & 31;
#pragma unroll
  for (int tt = 0; tt < 4; ++tt) {
#pragma unroll
    for (int reg = 0; reg < 16; ++reg) {
      int rr = rb + (reg & 3) + 8 * (reg >> 2);
      __builtin_nontemporal_store(acc[tt][reg],
          &C[(size_t)(i0 + rr) * NN + j0 + tt * 32 + col]);
    }
  }
}

extern "C" void kernel_launch(void* const* d_in, const int* in_sizes, int n_in,
                              void* d_out, int out_size, void* d_ws, size_t ws_size,
                              hipStream_t stream) {
  const float* x  = (const float*)d_in[0];
  const int*   ei = (const int*)d_in[1];
  const float* ew = (const float*)d_in[2];
  const float* W1 = (const float*)d_in[3];
  const float* W2 = (const float*)d_in[4];
  const float* W3 = (const float*)d_in[5];

  float* out    = (float*)d_out;
  float* adj    = out;                                   // [8192,8192]
  float* mu     = out + (size_t)NN * NN;                 // [8192,128]
  float* logv   = mu + (size_t)NN * 128;                 // [8192,128]
  float* z      = logv + (size_t)NN * 128;               // [8192,128]

  const int* srcp = ei;
  const int* dstp = ei + NE;

  char* ws = (char*)d_ws;
  size_t off = 0;
  auto alloc = [&](size_t b) -> void* {
    void* p = ws + off;
    off = (off + b + 255) & ~(size_t)255;
    return p;
  };
  u16* xh   = (u16*)alloc((size_t)NN * 512 * 2);
  u16* xl   = (u16*)alloc((size_t)NN * 512 * 2);
  u16* W1h  = (u16*)alloc(512 * 256 * 2);   // col-major [256][512]
  u16* W1l  = (u16*)alloc(512 * 256 * 2);
  u16* W23h = (u16*)alloc(256 * 256 * 2);   // col-major [256][256]
  u16* W23l = (u16*)alloc(256 * 256 * 2);
  float* h0 = (float*)alloc((size_t)NN * 256 * 4);
  u16* h0b  = (u16*)alloc((size_t)NN * 256 * 2);   // bf16 copy for gather
  u16* h1h  = (u16*)alloc((size_t)NN * 256 * 2);
  u16* h1l  = (u16*)alloc((size_t)NN * 256 * 2);
  float* H2 = (float*)alloc((size_t)NN * 256 * 4);
  u16* H2b  = (u16*)alloc((size_t)NN * 256 * 2);   // bf16 copy for gather
  u16* zb   = (u16*)alloc((size_t)NN * 128 * 2);
  int* deg      = (int*)alloc(NN * 4);
  int* rowptr   = (int*)alloc((NN + 1) * 4);
  int* cursor   = (int*)alloc(NN * 4);
  int* csr_src  = (int*)alloc((size_t)NE * 4);
  float* csr_w  = (float*)alloc((size_t)NE * 4);

  hipMemsetAsync(deg, 0, NN * 4, stream);

  // converts
  split_x<<<(NN * 512 / 4) / 256, 256, 0, stream>>>(x, xh, xl);
  splitT_w1<<<(512 * 256) / 256, 256, 0, stream>>>(W1, W1h, W1l);
  build_w23T<<<(256 * 256) / 256, 256, 0, stream>>>(W2, W3, W23h, W23l);

  // CSR build
  hist_kernel<<<NE / 256, 256, 0, stream>>>(dstp, deg);
  scan_kernel<<<1, 1024, 0, stream>>>(deg, rowptr, cursor);
  scatter_kernel<<<NE / 256, 256, 0, stream>>>(srcp, dstp, ew, cursor, csr_src, csr_w);

  // h0 = x @ W1 (f32) ; h0b = bf16(h0)
  gemm_split_kernel<<<dim3(NN / 64, 256 / 64), 256, 0, stream>>>(xh, xl, W1h, W1l, h0,
                                                                 NN, 256, 512);
  conv_bf16<<<(NN * 256 / 4) / 256, 256, 0, stream>>>(h0, h0b);
  // h1 = relu(spmm(h0b)) -> split hi/lo
  spmm_relu_kernel<<<NN / 4, 256, 0, stream>>>(rowptr, csr_src, csr_w, h0b, h1h, h1l);
  // H2 = h1 @ [W2|W3] (f32) ; H2b = bf16(H2)
  gemm_split_kernel<<<dim3(NN / 64, 256 / 64), 256, 0, stream>>>(h1h, h1l, W23h, W23l, H2,
                                                                 NN, 256, 256);
  conv_bf16<<<(NN * 256 / 4) / 256, 256, 0, stream>>>(H2, H2b);
  // mu/logvar = spmm(H2b); z = mu; zb = bf16(mu)
  spmm_out_kernel<<<NN / 4, 256, 0, stream>>>(rowptr, csr_src, csr_w, H2b, mu, logv, z, zb);
  // adj = z @ z^T  (A-in-reg, B-in-LDS, 4 blocks/CU)
  zzt_kernel<<<dim3(NN / 128, NN / 128), 256, 0, stream>>>(zb, adj);
}

// Round 10
// 199.839 us; speedup vs baseline: 1.4237x; 1.0774x over previous
//
#include <hip/hip_runtime.h>
#include <hip/hip_bf16.h>

#define NN 8192
#define NE 262144

typedef __attribute__((ext_vector_type(8))) short bf16x8;
typedef __attribute__((ext_vector_type(4))) float f32x4;
typedef __attribute__((ext_vector_type(16))) float f32x16;
typedef unsigned short u16;
typedef __attribute__((ext_vector_type(4))) u16 u16x4;

__device__ inline u16 f2b(float f) {
  unsigned u = __float_as_uint(f);
  unsigned r = u + 0x7FFF + ((u >> 16) & 1);   // RNE to bf16
  return (u16)(r >> 16);
}
__device__ inline float b2f(u16 b) {
  return __uint_as_float(((unsigned)b) << 16);
}

// ---------- fused converts: x split (4096 blks) | W1^T split (512) | W23^T (256) ----
__global__ void prep_kernel(const float* __restrict__ x, const float* __restrict__ W1,
                            const float* __restrict__ W2, const float* __restrict__ W3,
                            u16* __restrict__ xh, u16* __restrict__ xl,
                            u16* __restrict__ W1h, u16* __restrict__ W1l,
                            u16* __restrict__ W23h, u16* __restrict__ W23l) {
  int b = blockIdx.x;
  if (b < 4096) {
    int i = (b * 256 + threadIdx.x) * 4;
    f32x4 v = *(const f32x4*)(x + i);
    u16x4 vh, vl;
#pragma unroll
    for (int j = 0; j < 4; ++j) {
      u16 h = f2b(v[j]);
      vh[j] = h;
      vl[j] = f2b(v[j] - b2f(h));
    }
    *(u16x4*)(xh + i) = vh;
    *(u16x4*)(xl + i) = vl;
  } else if (b < 4096 + 512) {
    int i = (b - 4096) * 256 + threadIdx.x;   // 512*256 elems
    int k = i >> 8, n = i & 255;
    float v = W1[i];
    u16 h = f2b(v);
    W1h[(size_t)n * 512 + k] = h;
    W1l[(size_t)n * 512 + k] = f2b(v - b2f(h));
  } else {
    int i = (b - 4608) * 256 + threadIdx.x;   // 65536 elems
    int k = i >> 8, j = i & 255;
    float v = (j < 128) ? W2[(k << 7) + j] : W3[(k << 7) + (j - 128)];
    u16 h = f2b(v);
    W23h[(size_t)j * 256 + k] = h;
    W23l[(size_t)j * 256 + k] = f2b(v - b2f(h));
  }
}

// ---------- CSR build ----------
__global__ void hist_kernel(const int* __restrict__ dst, int* __restrict__ deg) {
  int i = blockIdx.x * blockDim.x + threadIdx.x;
  if (i < NE) atomicAdd(&deg[dst[i]], 1);
}

__global__ void scan_kernel(const int* __restrict__ deg, int* __restrict__ rowptr,
                            int* __restrict__ cursor) {
  __shared__ int sums[1024];
  int t = threadIdx.x;
  int loc[8];
  int s = 0;
#pragma unroll
  for (int j = 0; j < 8; ++j) { s += deg[t * 8 + j]; loc[j] = s; }
  sums[t] = s;
  __syncthreads();
  for (int off = 1; off < 1024; off <<= 1) {
    int v = (t >= off) ? sums[t - off] : 0;
    __syncthreads();
    sums[t] += v;
    __syncthreads();
  }
  int base = (t > 0) ? sums[t - 1] : 0;
  if (t == 0) rowptr[0] = 0;
#pragma unroll
  for (int j = 0; j < 8; ++j) {
    rowptr[t * 8 + j + 1] = base + loc[j];
    cursor[t * 8 + j] = base + (j ? loc[j - 1] : 0);
  }
}

__global__ void scatter_kernel(const int* __restrict__ src, const int* __restrict__ dst,
                               const float* __restrict__ w, int* cursor,
                               int* __restrict__ csr_src, float* __restrict__ csr_w) {
  int i = blockIdx.x * blockDim.x + threadIdx.x;
  if (i >= NE) return;
  int d = dst[i];
  int p = atomicAdd(&cursor[d], 1);
  csr_src[p] = src[i];
  csr_w[p] = w[i];
}

// ---------- split GEMM: C = bf16(A(MxK)@B(KxN)); B packed col-major ----------
// block 256 / 4 waves; wave = 16 rows x 64 cols; grid (M/64, N/64)
__global__ void gemm_split_kernel(const u16* __restrict__ Ah, const u16* __restrict__ Al,
                                  const u16* __restrict__ Bh, const u16* __restrict__ Bl,
                                  u16* __restrict__ C, int M, int N, int K) {
  int wave = threadIdx.x >> 6, lane = threadIdx.x & 63;
  int r = lane & 15, kf = (lane >> 4) * 8;
  int row = blockIdx.x * 64 + wave * 16 + r;
  int col0 = blockIdx.y * 64;
  f32x4 acc[4] = {};
  for (int k0 = 0; k0 < K; k0 += 32) {
    int ka = k0 + kf;
    bf16x8 ah = *(const bf16x8*)(Ah + (size_t)row * K + ka);
    bf16x8 al = *(const bf16x8*)(Al + (size_t)row * K + ka);
#pragma unroll
    for (int t = 0; t < 4; ++t) {
      int col = col0 + t * 16 + r;
      bf16x8 bh = *(const bf16x8*)(Bh + (size_t)col * K + ka);
      bf16x8 bl = *(const bf16x8*)(Bl + (size_t)col * K + ka);
      acc[t] = __builtin_amdgcn_mfma_f32_16x16x32_bf16(ah, bh, acc[t], 0, 0, 0);
      acc[t] = __builtin_amdgcn_mfma_f32_16x16x32_bf16(al, bh, acc[t], 0, 0, 0);
      acc[t] = __builtin_amdgcn_mfma_f32_16x16x32_bf16(ah, bl, acc[t], 0, 0, 0);
    }
  }
  int orow = blockIdx.x * 64 + wave * 16 + (lane >> 4) * 4;
#pragma unroll
  for (int t = 0; t < 4; ++t)
#pragma unroll
    for (int q = 0; q < 4; ++q)
      C[(size_t)(orow + q) * N + col0 + t * 16 + r] = f2b(acc[t][q]);
}

// ---------- spmm (CSR): 4 nodes/block, 64 lanes/node, bf16x4 gather, 4-deep ----
__global__ void spmm_relu_kernel(const int* __restrict__ rowptr, const int* __restrict__ csr_src,
                                 const float* __restrict__ csr_w, const u16* __restrict__ h,
                                 u16* __restrict__ oh, u16* __restrict__ ol) {
  int n = blockIdx.x * 4 + (threadIdx.x >> 6);
  int c = (threadIdx.x & 63) * 4;
  int e0 = rowptr[n], e1 = rowptr[n + 1];
  f32x4 acc = {};
  int i = e0;
  for (; i + 4 <= e1; i += 4) {
    int s0 = csr_src[i], s1 = csr_src[i + 1], s2 = csr_src[i + 2], s3 = csr_src[i + 3];
    float w0 = csr_w[i], w1 = csr_w[i + 1], w2 = csr_w[i + 2], w3 = csr_w[i + 3];
    u16x4 v0 = *(const u16x4*)(h + (size_t)s0 * 256 + c);
    u16x4 v1 = *(const u16x4*)(h + (size_t)s1 * 256 + c);
    u16x4 v2 = *(const u16x4*)(h + (size_t)s2 * 256 + c);
    u16x4 v3 = *(const u16x4*)(h + (size_t)s3 * 256 + c);
#pragma unroll
    for (int j = 0; j < 4; ++j) {
      acc[j] = fmaf(w0, b2f(v0[j]), acc[j]);
      acc[j] = fmaf(w1, b2f(v1[j]), acc[j]);
      acc[j] = fmaf(w2, b2f(v2[j]), acc[j]);
      acc[j] = fmaf(w3, b2f(v3[j]), acc[j]);
    }
  }
  for (; i < e1; ++i) {
    float w0 = csr_w[i];
    u16x4 v0 = *(const u16x4*)(h + (size_t)csr_src[i] * 256 + c);
#pragma unroll
    for (int j = 0; j < 4; ++j) acc[j] = fmaf(w0, b2f(v0[j]), acc[j]);
  }
  u16x4 vh, vl;
#pragma unroll
  for (int j = 0; j < 4; ++j) {
    float a = fmaxf(acc[j], 0.f);
    u16 hb = f2b(a);
    vh[j] = hb;
    vl[j] = f2b(a - b2f(hb));
  }
  *(u16x4*)(oh + (size_t)n * 256 + c) = vh;
  *(u16x4*)(ol + (size_t)n * 256 + c) = vl;
}

__global__ void spmm_out_kernel(const int* __restrict__ rowptr, const int* __restrict__ csr_src,
                                const float* __restrict__ csr_w, const u16* __restrict__ h,
                                float* __restrict__ mu, float* __restrict__ logvar,
                                float* __restrict__ z, u16* __restrict__ zb) {
  int n = blockIdx.x * 4 + (threadIdx.x >> 6);
  int c = (threadIdx.x & 63) * 4;
  int e0 = rowptr[n], e1 = rowptr[n + 1];
  f32x4 acc = {};
  int i = e0;
  for (; i + 4 <= e1; i += 4) {
    int s0 = csr_src[i], s1 = csr_src[i + 1], s2 = csr_src[i + 2], s3 = csr_src[i + 3];
    float w0 = csr_w[i], w1 = csr_w[i + 1], w2 = csr_w[i + 2], w3 = csr_w[i + 3];
    u16x4 v0 = *(const u16x4*)(h + (size_t)s0 * 256 + c);
    u16x4 v1 = *(const u16x4*)(h + (size_t)s1 * 256 + c);
    u16x4 v2 = *(const u16x4*)(h + (size_t)s2 * 256 + c);
    u16x4 v3 = *(const u16x4*)(h + (size_t)s3 * 256 + c);
#pragma unroll
    for (int j = 0; j < 4; ++j) {
      acc[j] = fmaf(w0, b2f(v0[j]), acc[j]);
      acc[j] = fmaf(w1, b2f(v1[j]), acc[j]);
      acc[j] = fmaf(w2, b2f(v2[j]), acc[j]);
      acc[j] = fmaf(w3, b2f(v3[j]), acc[j]);
    }
  }
  for (; i < e1; ++i) {
    float w0 = csr_w[i];
    u16x4 v0 = *(const u16x4*)(h + (size_t)csr_src[i] * 256 + c);
#pragma unroll
    for (int j = 0; j < 4; ++j) acc[j] = fmaf(w0, b2f(v0[j]), acc[j]);
  }
  if (c < 128) {
    *(f32x4*)(mu + (size_t)n * 128 + c) = acc;
    *(f32x4*)(z + (size_t)n * 128 + c) = acc;
    u16x4 vb;
#pragma unroll
    for (int j = 0; j < 4; ++j) vb[j] = f2b(acc[j]);
    *(u16x4*)(zb + (size_t)n * 128 + c) = vb;
  } else {
    *(f32x4*)(logvar + (size_t)n * 128 + (c - 128)) = acc;
  }
}

// ---------- adj = Z @ Z^T, Z [8192][128] bf16 ----------
// v3b (R7): A in registers, B in 32KB swizzled LDS -> 4 blocks/CU.
// block 256 / 4 waves; tile 128x128; wave = 32 rows x 128 cols; grid (64,64).
__global__ void zzt_kernel(const u16* __restrict__ Z, float* __restrict__ C) {
  __shared__ u16 lB[128 * 128];   // 32KB swizzled (rows = C cols)
  int t = threadIdx.x;
  int i0 = blockIdx.y * 128;
  int j0 = blockIdx.x * 128;
  const char* gB = (const char*)(Z + (size_t)j0 * 128);
#pragma unroll
  for (int cix = 0; cix < 8; ++cix) {
    int p = (cix * 256 + t) * 16;
    int row = p >> 8;
    int sw = (p & 255) ^ ((row & 15) << 4);
    bf16x8 vb = *(const bf16x8*)(gB + p);
    *(bf16x8*)((char*)lB + row * 256 + sw) = vb;
  }
  int wave = t >> 6, lane = t & 63;
  int lrow = lane & 31, hi = lane >> 5;
  const u16* aRow = Z + (size_t)(i0 + wave * 32 + lrow) * 128 + hi * 8;
  bf16x8 a[8];
#pragma unroll
  for (int k = 0; k < 8; ++k)
    a[k] = *(const bf16x8*)(aRow + k * 16);
  __syncthreads();
  f32x16 acc[4] = {};
#pragma unroll
  for (int ks = 0; ks < 8; ++ks) {
    int kb = ks * 32 + hi * 16;
#pragma unroll
    for (int tt = 0; tt < 4; ++tt) {
      int brow = tt * 32 + lrow;
      bf16x8 b = *(const bf16x8*)((const char*)lB + brow * 256 + (kb ^ ((brow & 15) << 4)));
      acc[tt] = __builtin_amdgcn_mfma_f32_32x32x16_bf16(a[ks], b, acc[tt], 0, 0, 0);
    }
  }
  int rb = wave * 32 + 4 * (lane >> 5);
  int col = lane & 31;
#pragma unroll
  for (int tt = 0; tt < 4; ++tt) {
#pragma unroll
    for (int reg = 0; reg < 16; ++reg) {
      int rr = rb + (reg & 3) + 8 * (reg >> 2);
      __builtin_nontemporal_store(acc[tt][reg],
          &C[(size_t)(i0 + rr) * NN + j0 + tt * 32 + col]);
    }
  }
}

extern "C" void kernel_launch(void* const* d_in, const int* in_sizes, int n_in,
                              void* d_out, int out_size, void* d_ws, size_t ws_size,
                              hipStream_t stream) {
  const float* x  = (const float*)d_in[0];
  const int*   ei = (const int*)d_in[1];
  const float* ew = (const float*)d_in[2];
  const float* W1 = (const float*)d_in[3];
  const float* W2 = (const float*)d_in[4];
  const float* W3 = (const float*)d_in[5];

  float* out    = (float*)d_out;
  float* adj    = out;                                   // [8192,8192]
  float* mu     = out + (size_t)NN * NN;                 // [8192,128]
  float* logv   = mu + (size_t)NN * 128;                 // [8192,128]
  float* z      = logv + (size_t)NN * 128;               // [8192,128]

  const int* srcp = ei;
  const int* dstp = ei + NE;

  char* ws = (char*)d_ws;
  size_t off = 0;
  auto alloc = [&](size_t b) -> void* {
    void* p = ws + off;
    off = (off + b + 255) & ~(size_t)255;
    return p;
  };
  u16* xh   = (u16*)alloc((size_t)NN * 512 * 2);
  u16* xl   = (u16*)alloc((size_t)NN * 512 * 2);
  u16* W1h  = (u16*)alloc(512 * 256 * 2);   // col-major [256][512]
  u16* W1l  = (u16*)alloc(512 * 256 * 2);
  u16* W23h = (u16*)alloc(256 * 256 * 2);   // col-major [256][256]
  u16* W23l = (u16*)alloc(256 * 256 * 2);
  u16* h0b  = (u16*)alloc((size_t)NN * 256 * 2);   // bf16(x@W1)
  u16* h1h  = (u16*)alloc((size_t)NN * 256 * 2);
  u16* h1l  = (u16*)alloc((size_t)NN * 256 * 2);
  u16* H2b  = (u16*)alloc((size_t)NN * 256 * 2);   // bf16(h1@W23)
  u16* zb   = (u16*)alloc((size_t)NN * 128 * 2);
  int* deg      = (int*)alloc(NN * 4);
  int* rowptr   = (int*)alloc((NN + 1) * 4);
  int* cursor   = (int*)alloc(NN * 4);
  int* csr_src  = (int*)alloc((size_t)NE * 4);
  float* csr_w  = (float*)alloc((size_t)NE * 4);

  hipMemsetAsync(deg, 0, NN * 4, stream);

  // fused converts
  prep_kernel<<<4096 + 512 + 256, 256, 0, stream>>>(x, W1, W2, W3, xh, xl,
                                                    W1h, W1l, W23h, W23l);

  // CSR build
  hist_kernel<<<NE / 256, 256, 0, stream>>>(dstp, deg);
  scan_kernel<<<1, 1024, 0, stream>>>(deg, rowptr, cursor);
  scatter_kernel<<<NE / 256, 256, 0, stream>>>(srcp, dstp, ew, cursor, csr_src, csr_w);

  // h0b = bf16(x @ W1)
  gemm_split_kernel<<<dim3(NN / 64, 256 / 64), 256, 0, stream>>>(xh, xl, W1h, W1l, h0b,
                                                                 NN, 256, 512);
  // h1 = relu(spmm(h0b)) -> split hi/lo
  spmm_relu_kernel<<<NN / 4, 256, 0, stream>>>(rowptr, csr_src, csr_w, h0b, h1h, h1l);
  // H2b = bf16(h1 @ [W2|W3])
  gemm_split_kernel<<<dim3(NN / 64, 256 / 64), 256, 0, stream>>>(h1h, h1l, W23h, W23l, H2b,
                                                                 NN, 256, 256);
  // mu/logvar = spmm(H2b); z = mu; zb = bf16(mu)
  spmm_out_kernel<<<NN / 4, 256, 0, stream>>>(rowptr, csr_src, csr_w, H2b, mu, logv, z, zb);
  // adj = z @ z^T  (A-in-reg, B-in-LDS, 4 blocks/CU)
  zzt_kernel<<<dim3(NN / 128, NN / 128), 256, 0, stream>>>(zb, adj);
}

// Round 11
// 165.765 us; speedup vs baseline: 1.7164x; 1.2056x over previous
//
#include <hip/hip_runtime.h>
#include <hip/hip_bf16.h>

#define NN 8192
#define NE 262144

typedef __attribute__((ext_vector_type(8))) short bf16x8;
typedef __attribute__((ext_vector_type(4))) float f32x4;
typedef __attribute__((ext_vector_type(16))) float f32x16;
typedef unsigned short u16;
typedef __attribute__((ext_vector_type(4))) u16 u16x4;

__device__ inline u16 f2b(float f) {
  unsigned u = __float_as_uint(f);
  unsigned r = u + 0x7FFF + ((u >> 16) & 1);   // RNE to bf16
  return (u16)(r >> 16);
}
__device__ inline float b2f(u16 b) {
  return __uint_as_float(((unsigned)b) << 16);
}

// ---------- fused prep: x->bf16 (4096 blks) | W1^T (512) | W23^T (256) | hist (1024) --
__global__ void prep_kernel(const float* __restrict__ x, const float* __restrict__ W1,
                            const float* __restrict__ W2, const float* __restrict__ W3,
                            const int* __restrict__ dst, int* __restrict__ deg,
                            u16* __restrict__ xb, u16* __restrict__ W1T,
                            u16* __restrict__ W23T) {
  int b = blockIdx.x;
  if (b < 4096) {
    int i = (b * 256 + threadIdx.x) * 4;
    f32x4 v = *(const f32x4*)(x + i);
    u16x4 o;
#pragma unroll
    for (int j = 0; j < 4; ++j) o[j] = f2b(v[j]);
    *(u16x4*)(xb + i) = o;
  } else if (b < 4096 + 512) {
    int i = (b - 4096) * 256 + threadIdx.x;   // 512*256 elems
    int k = i >> 8, n = i & 255;
    W1T[(size_t)n * 512 + k] = f2b(W1[i]);
  } else if (b < 4096 + 512 + 256) {
    int i = (b - 4608) * 256 + threadIdx.x;   // 65536 elems
    int k = i >> 8, j = i & 255;
    float v = (j < 128) ? W2[(k << 7) + j] : W3[(k << 7) + (j - 128)];
    W23T[(size_t)j * 256 + k] = f2b(v);
  } else {
    int i = (b - 4864) * 256 + threadIdx.x;   // NE elems
    if (i < NE) atomicAdd(&deg[dst[i]], 1);
  }
}

// ---------- CSR build ----------
__global__ void scan_kernel(const int* __restrict__ deg, int* __restrict__ rowptr,
                            int* __restrict__ cursor) {
  __shared__ int sums[1024];
  int t = threadIdx.x;
  int loc[8];
  int s = 0;
#pragma unroll
  for (int j = 0; j < 8; ++j) { s += deg[t * 8 + j]; loc[j] = s; }
  sums[t] = s;
  __syncthreads();
  for (int off = 1; off < 1024; off <<= 1) {
    int v = (t >= off) ? sums[t - off] : 0;
    __syncthreads();
    sums[t] += v;
    __syncthreads();
  }
  int base = (t > 0) ? sums[t - 1] : 0;
  if (t == 0) rowptr[0] = 0;
#pragma unroll
  for (int j = 0; j < 8; ++j) {
    rowptr[t * 8 + j + 1] = base + loc[j];
    cursor[t * 8 + j] = base + (j ? loc[j - 1] : 0);
  }
}

__global__ void scatter_kernel(const int* __restrict__ src, const int* __restrict__ dst,
                               const float* __restrict__ w, int* cursor,
                               int* __restrict__ csr_src, float* __restrict__ csr_w) {
  int i = blockIdx.x * blockDim.x + threadIdx.x;
  if (i >= NE) return;
  int d = dst[i];
  int p = atomicAdd(&cursor[d], 1);
  csr_src[p] = src[i];
  csr_w[p] = w[i];
}

// ---------- plain bf16 GEMM: C = bf16(A(MxK) @ B(KxN)); B packed col-major [N][K] --
// block 256 / 4 waves; wave = 16 rows x 64 cols; grid (M/64, N/64)
__global__ void gemm_plain_kernel(const u16* __restrict__ A, const u16* __restrict__ BT,
                                  u16* __restrict__ C, int M, int N, int K) {
  int wave = threadIdx.x >> 6, lane = threadIdx.x & 63;
  int r = lane & 15, kf = (lane >> 4) * 8;
  int row = blockIdx.x * 64 + wave * 16 + r;
  int col0 = blockIdx.y * 64;
  f32x4 acc[4] = {};
  for (int k0 = 0; k0 < K; k0 += 32) {
    int ka = k0 + kf;
    bf16x8 a = *(const bf16x8*)(A + (size_t)row * K + ka);
#pragma unroll
    for (int t = 0; t < 4; ++t) {
      bf16x8 b = *(const bf16x8*)(BT + (size_t)(col0 + t * 16 + r) * K + ka);
      acc[t] = __builtin_amdgcn_mfma_f32_16x16x32_bf16(a, b, acc[t], 0, 0, 0);
    }
  }
  int orow = blockIdx.x * 64 + wave * 16 + (lane >> 4) * 4;
#pragma unroll
  for (int t = 0; t < 4; ++t)
#pragma unroll
    for (int q = 0; q < 4; ++q)
      C[(size_t)(orow + q) * N + col0 + t * 16 + r] = f2b(acc[t][q]);
}

// ---------- spmm (CSR): 4 nodes/block, 64 lanes/node, bf16x4 gather, 4-deep ----
__global__ void spmm_relu_kernel(const int* __restrict__ rowptr, const int* __restrict__ csr_src,
                                 const float* __restrict__ csr_w, const u16* __restrict__ h,
                                 u16* __restrict__ o) {
  int n = blockIdx.x * 4 + (threadIdx.x >> 6);
  int c = (threadIdx.x & 63) * 4;
  int e0 = rowptr[n], e1 = rowptr[n + 1];
  f32x4 acc = {};
  int i = e0;
  for (; i + 4 <= e1; i += 4) {
    int s0 = csr_src[i], s1 = csr_src[i + 1], s2 = csr_src[i + 2], s3 = csr_src[i + 3];
    float w0 = csr_w[i], w1 = csr_w[i + 1], w2 = csr_w[i + 2], w3 = csr_w[i + 3];
    u16x4 v0 = *(const u16x4*)(h + (size_t)s0 * 256 + c);
    u16x4 v1 = *(const u16x4*)(h + (size_t)s1 * 256 + c);
    u16x4 v2 = *(const u16x4*)(h + (size_t)s2 * 256 + c);
    u16x4 v3 = *(const u16x4*)(h + (size_t)s3 * 256 + c);
#pragma unroll
    for (int j = 0; j < 4; ++j) {
      acc[j] = fmaf(w0, b2f(v0[j]), acc[j]);
      acc[j] = fmaf(w1, b2f(v1[j]), acc[j]);
      acc[j] = fmaf(w2, b2f(v2[j]), acc[j]);
      acc[j] = fmaf(w3, b2f(v3[j]), acc[j]);
    }
  }
  for (; i < e1; ++i) {
    float w0 = csr_w[i];
    u16x4 v0 = *(const u16x4*)(h + (size_t)csr_src[i] * 256 + c);
#pragma unroll
    for (int j = 0; j < 4; ++j) acc[j] = fmaf(w0, b2f(v0[j]), acc[j]);
  }
  u16x4 vh;
#pragma unroll
  for (int j = 0; j < 4; ++j) vh[j] = f2b(fmaxf(acc[j], 0.f));
  *(u16x4*)(o + (size_t)n * 256 + c) = vh;
}

__global__ void spmm_out_kernel(const int* __restrict__ rowptr, const int* __restrict__ csr_src,
                                const float* __restrict__ csr_w, const u16* __restrict__ h,
                                float* __restrict__ mu, float* __restrict__ logvar,
                                float* __restrict__ z, u16* __restrict__ zb) {
  int n = blockIdx.x * 4 + (threadIdx.x >> 6);
  int c = (threadIdx.x & 63) * 4;
  int e0 = rowptr[n], e1 = rowptr[n + 1];
  f32x4 acc = {};
  int i = e0;
  for (; i + 4 <= e1; i += 4) {
    int s0 = csr_src[i], s1 = csr_src[i + 1], s2 = csr_src[i + 2], s3 = csr_src[i + 3];
    float w0 = csr_w[i], w1 = csr_w[i + 1], w2 = csr_w[i + 2], w3 = csr_w[i + 3];
    u16x4 v0 = *(const u16x4*)(h + (size_t)s0 * 256 + c);
    u16x4 v1 = *(const u16x4*)(h + (size_t)s1 * 256 + c);
    u16x4 v2 = *(const u16x4*)(h + (size_t)s2 * 256 + c);
    u16x4 v3 = *(const u16x4*)(h + (size_t)s3 * 256 + c);
#pragma unroll
    for (int j = 0; j < 4; ++j) {
      acc[j] = fmaf(w0, b2f(v0[j]), acc[j]);
      acc[j] = fmaf(w1, b2f(v1[j]), acc[j]);
      acc[j] = fmaf(w2, b2f(v2[j]), acc[j]);
      acc[j] = fmaf(w3, b2f(v3[j]), acc[j]);
    }
  }
  for (; i < e1; ++i) {
    float w0 = csr_w[i];
    u16x4 v0 = *(const u16x4*)(h + (size_t)csr_src[i] * 256 + c);
#pragma unroll
    for (int j = 0; j < 4; ++j) acc[j] = fmaf(w0, b2f(v0[j]), acc[j]);
  }
  if (c < 128) {
    *(f32x4*)(mu + (size_t)n * 128 + c) = acc;
    *(f32x4*)(z + (size_t)n * 128 + c) = acc;
    u16x4 vb;
#pragma unroll
    for (int j = 0; j < 4; ++j) vb[j] = f2b(acc[j]);
    *(u16x4*)(zb + (size_t)n * 128 + c) = vb;
  } else {
    *(f32x4*)(logvar + (size_t)n * 128 + (c - 128)) = acc;
  }
}

// ---------- adj = Z @ Z^T, Z [8192][128] bf16 ----------
// v3b (R7): A in registers, B in 32KB swizzled LDS -> 4 blocks/CU.
// block 256 / 4 waves; tile 128x128; wave = 32 rows x 128 cols; grid (64,64).
__global__ void zzt_kernel(const u16* __restrict__ Z, float* __restrict__ C) {
  __shared__ u16 lB[128 * 128];   // 32KB swizzled (rows = C cols)
  int t = threadIdx.x;
  int i0 = blockIdx.y * 128;
  int j0 = blockIdx.x * 128;
  const char* gB = (const char*)(Z + (size_t)j0 * 128);
#pragma unroll
  for (int cix = 0; cix < 8; ++cix) {
    int p = (cix * 256 + t) * 16;
    int row = p >> 8;
    int sw = (p & 255) ^ ((row & 15) << 4);
    bf16x8 vb = *(const bf16x8*)(gB + p);
    *(bf16x8*)((char*)lB + row * 256 + sw) = vb;
  }
  int wave = t >> 6, lane = t & 63;
  int lrow = lane & 31, hi = lane >> 5;
  const u16* aRow = Z + (size_t)(i0 + wave * 32 + lrow) * 128 + hi * 8;
  bf16x8 a[8];
#pragma unroll
  for (int k = 0; k < 8; ++k)
    a[k] = *(const bf16x8*)(aRow + k * 16);
  __syncthreads();
  f32x16 acc[4] = {};
#pragma unroll
  for (int ks = 0; ks < 8; ++ks) {
    int kb = ks * 32 + hi * 16;
#pragma unroll
    for (int tt = 0; tt < 4; ++tt) {
      int brow = tt * 32 + lrow;
      bf16x8 b = *(const bf16x8*)((const char*)lB + brow * 256 + (kb ^ ((brow & 15) << 4)));
      acc[tt] = __builtin_amdgcn_mfma_f32_32x32x16_bf16(a[ks], b, acc[tt], 0, 0, 0);
    }
  }
  int rb = wave * 32 + 4 * (lane >> 5);
  int col = lane & 31;
#pragma unroll
  for (int tt = 0; tt < 4; ++tt) {
#pragma unroll
    for (int reg = 0; reg < 16; ++reg) {
      int rr = rb + (reg & 3) + 8 * (reg >> 2);
      __builtin_nontemporal_store(acc[tt][reg],
          &C[(size_t)(i0 + rr) * NN + j0 + tt * 32 + col]);
    }
  }
}

extern "C" void kernel_launch(void* const* d_in, const int* in_sizes, int n_in,
                              void* d_out, int out_size, void* d_ws, size_t ws_size,
                              hipStream_t stream) {
  const float* x  = (const float*)d_in[0];
  const int*   ei = (const int*)d_in[1];
  const float* ew = (const float*)d_in[2];
  const float* W1 = (const float*)d_in[3];
  const float* W2 = (const float*)d_in[4];
  const float* W3 = (const float*)d_in[5];

  float* out    = (float*)d_out;
  float* adj    = out;                                   // [8192,8192]
  float* mu     = out + (size_t)NN * NN;                 // [8192,128]
  float* logv   = mu + (size_t)NN * 128;                 // [8192,128]
  float* z      = logv + (size_t)NN * 128;               // [8192,128]

  const int* srcp = ei;
  const int* dstp = ei + NE;

  char* ws = (char*)d_ws;
  size_t off = 0;
  auto alloc = [&](size_t b) -> void* {
    void* p = ws + off;
    off = (off + b + 255) & ~(size_t)255;
    return p;
  };
  u16* xb   = (u16*)alloc((size_t)NN * 512 * 2);
  u16* W1T  = (u16*)alloc(512 * 256 * 2);   // col-major [256][512]
  u16* W23T = (u16*)alloc(256 * 256 * 2);   // col-major [256][256]
  u16* h0b  = (u16*)alloc((size_t)NN * 256 * 2);   // bf16(x@W1)
  u16* h1b  = (u16*)alloc((size_t)NN * 256 * 2);   // bf16(relu(spmm))
  u16* H2b  = (u16*)alloc((size_t)NN * 256 * 2);   // bf16(h1@W23)
  u16* zb   = (u16*)alloc((size_t)NN * 128 * 2);
  int* deg      = (int*)alloc(NN * 4);
  int* rowptr   = (int*)alloc((NN + 1) * 4);
  int* cursor   = (int*)alloc(NN * 4);
  int* csr_src  = (int*)alloc((size_t)NE * 4);
  float* csr_w  = (float*)alloc((size_t)NE * 4);

  hipMemsetAsync(deg, 0, NN * 4, stream);

  // fused converts + degree histogram
  prep_kernel<<<4096 + 512 + 256 + 1024, 256, 0, stream>>>(x, W1, W2, W3, dstp, deg,
                                                           xb, W1T, W23T);

  // CSR build
  scan_kernel<<<1, 1024, 0, stream>>>(deg, rowptr, cursor);
  scatter_kernel<<<NE / 256, 256, 0, stream>>>(srcp, dstp, ew, cursor, csr_src, csr_w);

  // h0b = bf16(x @ W1)
  gemm_plain_kernel<<<dim3(NN / 64, 256 / 64), 256, 0, stream>>>(xb, W1T, h0b,
                                                                 NN, 256, 512);
  // h1b = bf16(relu(spmm(h0b)))
  spmm_relu_kernel<<<NN / 4, 256, 0, stream>>>(rowptr, csr_src, csr_w, h0b, h1b);
  // H2b = bf16(h1 @ [W2|W3])
  gemm_plain_kernel<<<dim3(NN / 64, 256 / 64), 256, 0, stream>>>(h1b, W23T, H2b,
                                                                 NN, 256, 256);
  // mu/logvar = spmm(H2b); z = mu; zb = bf16(mu)
  spmm_out_kernel<<<NN / 4, 256, 0, stream>>>(rowptr, csr_src, csr_w, H2b, mu, logv, z, zb);
  // adj = z @ z^T  (A-in-reg, B-in-LDS, 4 blocks/CU)
  zzt_kernel<<<dim3(NN / 128, NN / 128), 256, 0, stream>>>(zb, adj);
}